// Round 9
// baseline (657.759 us; speedup 1.0000x reference)
//
#include <hip/hip_runtime.h>
#include <math.h>

#define Vc 5
#define Cc 32
#define Gc 8
#define Dc 32
#define Hc 192
#define Wc 192
#define HWc (Hc*Wc)
#define NSRC (Vc-1)
#define NBLK (HWc/16)    // 2304 single-wave blocks (16 px x 4 d_hi, 8 d per lane)

// output offsets (floats)
#define OFF_DEPTH  0
#define OFF_CONF   (HWc)
#define OFF_ATTN   (2*HWc)
#define OFF_EST    (OFF_ATTN + Dc*HWc)
#define OFF_SW     (OFF_EST + 3*HWc)
#define OFF_WEIGHT (OFF_SW + HWc)
#define OFF_NVAL   (OFF_WEIGHT + NSRC*HWc)
#define OFF_MIN    (OFF_NVAL + Dc*HWc)
#define OFF_MAX    (OFF_MIN + HWc)

// ws layout (floats):
//   [i*15 .. i*15+14]  per-view: rot(9), trans(3), norv(3)
//   [64..127]   per-block depth-min partials (64 blocks)
//   [128..191]  per-block depth-max partials
//   [256 ...]   transposed src features: (NSRC, HW, C) channels-last

#define WS_SRCT 256

__device__ void inv4(const float* A, float* out) {
    float M[4][8];
    for (int r = 0; r < 4; r++) {
        for (int c = 0; c < 4; c++) { M[r][c] = A[r*4+c]; M[r][c+4] = (r == c) ? 1.f : 0.f; }
    }
    for (int col = 0; col < 4; col++) {
        int piv = col; float best = fabsf(M[col][col]);
        for (int r = col+1; r < 4; r++) { float v = fabsf(M[r][col]); if (v > best) { best = v; piv = r; } }
        if (piv != col) for (int c = 0; c < 8; c++) { float t = M[col][c]; M[col][c] = M[piv][c]; M[piv][c] = t; }
        float inv = 1.f / M[col][col];
        for (int c = 0; c < 8; c++) M[col][c] *= inv;
        for (int r = 0; r < 4; r++) {
            if (r == col) continue;
            float f = M[r][col];
            for (int c = 0; c < 8; c++) M[r][c] -= f * M[col][c];
        }
    }
    for (int r = 0; r < 4; r++) for (int c = 0; c < 4; c++) out[r*4+c] = M[r][c+4];
}

__device__ void inv3(const float* A, float* out) {
    float a=A[0],b=A[1],c=A[2],d=A[3],e=A[4],f=A[5],g=A[6],h=A[7],i=A[8];
    float det = a*(e*i-f*h) - b*(d*i-f*g) + c*(d*h-e*g);
    float id = 1.f/det;
    out[0]=(e*i-f*h)*id; out[1]=(c*h-b*i)*id; out[2]=(b*f-c*e)*id;
    out[3]=(f*g-d*i)*id; out[4]=(a*i-c*g)*id; out[5]=(c*d-a*f)*id;
    out[6]=(d*h-e*g)*id; out[7]=(b*g-a*h)*id; out[8]=(a*e-b*d)*id;
}

__global__ __launch_bounds__(256)
void setup_minmax_kernel(const float* __restrict__ rotation,
                         const float* __restrict__ proj,
                         const float* __restrict__ depth,
                         float* __restrict__ wsf) {
    const int tid = blockIdx.x * 256 + threadIdx.x;
    const int n4 = (Dc*HWc) / 4;
    const float4* d4 = (const float4*)depth;
    float mn = 3.4e38f, mx = -3.4e38f;
    for (int idx = tid; idx < n4; idx += 64*256) {
        float4 v = d4[idx];
        mn = fminf(mn, fminf(fminf(v.x, v.y), fminf(v.z, v.w)));
        mx = fmaxf(mx, fmaxf(fmaxf(v.x, v.y), fmaxf(v.z, v.w)));
    }
    for (int off = 32; off; off >>= 1) {
        mn = fminf(mn, __shfl_xor(mn, off));
        mx = fmaxf(mx, __shfl_xor(mx, off));
    }
    __shared__ float smn[4], smx[4];
    const int w = threadIdx.x >> 6;
    if ((threadIdx.x & 63) == 0) { smn[w] = mn; smx[w] = mx; }
    __syncthreads();
    if (threadIdx.x == 0) {
        for (int k = 1; k < 4; k++) { mn = fminf(mn, smn[k]); mx = fmaxf(mx, smx[k]); }
        wsf[64 + blockIdx.x] = mn;
        wsf[128 + blockIdx.x] = mx;
        if (blockIdx.x == 0) {
            float refE[16], refK[16], refNew[16], invRef[16];
            for (int k = 0; k < 16; k++) { refE[k] = proj[k]; refK[k] = proj[16+k]; }
            for (int k = 0; k < 16; k++) refNew[k] = refE[k];
            for (int r = 0; r < 3; r++) for (int c = 0; c < 4; c++) {
                float s = 0.f;
                for (int k = 0; k < 3; k++) s += refK[r*4+k] * refE[k*4+c];
                refNew[r*4+c] = s;
            }
            inv4(refNew, invRef);
            float invR0[9];
            inv3(rotation, invR0);
            for (int i = 0; i < NSRC; i++) {
                const float* E = proj + (i+1)*32;
                const float* K = proj + (i+1)*32 + 16;
                float sNew[16];
                for (int k = 0; k < 16; k++) sNew[k] = E[k];
                for (int r = 0; r < 3; r++) for (int c = 0; c < 4; c++) {
                    float s = 0.f;
                    for (int k = 0; k < 3; k++) s += K[r*4+k] * E[k*4+c];
                    sNew[r*4+c] = s;
                }
                float P[16];
                for (int r = 0; r < 4; r++) for (int c = 0; c < 4; c++) {
                    float s = 0.f;
                    for (int k = 0; k < 4; k++) s += sNew[r*4+k] * invRef[k*4+c];
                    P[r*4+c] = s;
                }
                float* o = wsf + i*15;
                for (int r = 0; r < 3; r++) for (int c = 0; c < 3; c++) o[r*3+c] = P[r*4+c];
                for (int r = 0; r < 3; r++) o[9+r] = P[r*4+3];
                const float* Ri = rotation + (i+1)*9;
                for (int c = 0; c < 3; c++) {
                    float s = 0.f;
                    for (int k = 0; k < 3; k++) s += Ri[2*3+k] * invR0[k*3+c];
                    o[12+c] = s;
                }
            }
        }
    }
}

// (NSRC, C, HW) -> (NSRC, HW, C): LDS-tiled, 64 px x 32 ch per block.
__global__ __launch_bounds__(256)
void transpose_kernel(const float* __restrict__ src, float* __restrict__ dst) {
    __shared__ float lds[64*33];
    const int t = threadIdx.x;
    const int v = blockIdx.x / (HWc/64);
    const int j = blockIdx.x % (HWc/64);
    const int hw0 = j*64;
    const float* s = src + (size_t)v*Cc*HWc;
    float* o = dst + (size_t)v*HWc*Cc + (size_t)hw0*Cc;
#pragma unroll
    for (int r = 0; r < 8; r++) {
        int idx = t + r*256;
        int c = idx >> 6, p = idx & 63;
        lds[p*33+c] = s[c*HWc + hw0 + p];
    }
    __syncthreads();
#pragma unroll
    for (int r = 0; r < 8; r++) {
        int idx = t + r*256;
        int p = idx >> 5, c = idx & 31;
        o[idx] = lds[p*33+c];
    }
}

// Single-wave blocks: 64 lanes = 16 px x 4 d_hi; each lane owns 8 depths
// (d = d_hi*8 + k). All d-indexed global I/O is full-64B-line coalesced
// (R8's 292 MB write / 222 MB fetch amplification fix). d-reductions:
// in-register over k + shfl_xor(16), shfl_xor(32). Zero barriers, zero LDS.
// Register cut: cor_feats only feeds sum_g(w_reg*acc) -> keep ONE logit
// accumulator per depth instead of 8 group accumulators.
__global__ __launch_bounds__(64)
void main_kernel(const float* __restrict__ ref_feature,
                 const float* __restrict__ normal_plane,
                 const float* __restrict__ depth_hypo,
                 const float* __restrict__ w_reg,
                 const float* __restrict__ w_norm,
                 const float* __restrict__ wsf,
                 float* __restrict__ out) {
    const int lane = threadIdx.x;   // 0..63
    const int pxi = lane & 15;
    const int dhi = lane >> 4;      // 0..3
    // XCD-stripe swizzle: XCD k gets contiguous block range [k*288,(k+1)*288)
    const int bid = (blockIdx.x & 7) * (NBLK/8) + (blockIdx.x >> 3);
    const int bpix = bid * 16;      // 192%16==0 -> all 16 px share one row
    const int pix = bpix + pxi;
    const int y = pix / Wc;
    const int x = pix - y*Wc;
    const float fxp = (float)x;
    const float fyp = (float)y;

    // global hmin/hmax: full-wave butterfly over the 64 partials
    float hmn = wsf[64 + lane];
    float hmx = wsf[128 + lane];
#pragma unroll
    for (int off = 32; off; off >>= 1) {
        hmn = fminf(hmn, __shfl_xor(hmn, off));
        hmx = fmaxf(hmx, __shfl_xor(hmx, off));
    }

    float refv[Cc];
#pragma unroll
    for (int c = 0; c < Cc; c++) refv[c] = ref_feature[c*HWc + pix];
    float wregv[Gc];
#pragma unroll
    for (int gg = 0; gg < Gc; gg++) wregv[gg] = w_reg[gg];

    const float np0 = normal_plane[pix];
    const float np1 = normal_plane[HWc + pix];
    const float np2 = normal_plane[2*HWc + pix];

    float dep[8];
#pragma unroll
    for (int k = 0; k < 8; k++) dep[k] = depth_hypo[(dhi*8 + k)*HWc + pix];

    float acc_logit[8], cws[8], sumw[8], nval[8];
#pragma unroll
    for (int k = 0; k < 8; k++) {
        acc_logit[k] = 0.f; cws[k] = 1e-8f; sumw[k] = 1e-8f; nval[k] = 0.f;
    }

    for (int i = 0; i < NSRC; i++) {
        const float* Mv = wsf + i*15;
        const float r00=Mv[0], r01=Mv[1], r02=Mv[2];
        const float r10=Mv[3], r11=Mv[4], r12=Mv[5];
        const float r20=Mv[6], r21=Mv[7], r22=Mv[8];
        const float t0=Mv[9], t1=Mv[10], t2=Mv[11];
        const float nv0=Mv[12], nv1=Mv[13], nv2=Mv[14];

        const float b0 = r00*fxp + r01*fyp + r02;
        const float b1 = r10*fxp + r11*fyp + r12;
        const float b2 = r20*fxp + r21*fyp + r22;
        const float src_w = fmaxf(np0*nv0 + np1*nv1 + np2*nv2, 0.f) + 0.01f;
        const float* srcT = wsf + WS_SRCT + (size_t)i * HWc * Cc;

        float s_d[8], wcf[8], valid[8];
#pragma unroll
        for (int k = 0; k < 8; k++) {
            float z = b2*dep[k] + t2;
            if (z == 0.f) z = 1e-9f;
            const float sx = (b0*dep[k] + t0) / z;
            const float sy = (b1*dep[k] + t1) / z;

            const float fx0 = floorf(sx), fy0 = floorf(sy);
            const float wx = sx - fx0, wy = sy - fy0;
            const float fx1 = fx0 + 1.f, fy1 = fy0 + 1.f;
            const bool ix0 = (fx0 >= 0.f) && (fx0 <= (float)(Wc-1));
            const bool ix1 = (fx1 >= 0.f) && (fx1 <= (float)(Wc-1));
            const bool iy0 = (fy0 >= 0.f) && (fy0 <= (float)(Hc-1));
            const bool iy1 = (fy1 >= 0.f) && (fy1 <= (float)(Hc-1));
            const float w00 = (1.f-wx)*(1.f-wy) * ((ix0 && iy0) ? 1.f : 0.f);
            const float w10 = wx*(1.f-wy)       * ((ix1 && iy0) ? 1.f : 0.f);
            const float w01 = (1.f-wx)*wy       * ((ix0 && iy1) ? 1.f : 0.f);
            const float w11 = wx*wy             * ((ix1 && iy1) ? 1.f : 0.f);
            const int xi0 = (int)fminf(fmaxf(fx0, 0.f), (float)(Wc-1));
            const int xi1 = (int)fminf(fmaxf(fx1, 0.f), (float)(Wc-1));
            const int yi0 = (int)fminf(fmaxf(fy0, 0.f), (float)(Hc-1));
            const int yi1 = (int)fminf(fmaxf(fy1, 0.f), (float)(Hc-1));
            const int b00 = (yi0*Wc + xi0)*Cc, b10 = (yi0*Wc + xi1)*Cc;
            const int b01 = (yi1*Wc + xi0)*Cc, b11 = (yi1*Wc + xi1)*Cc;

            float sdk = 0.f, wck = 0.f, vk = 0.f;
#pragma unroll
            for (int q = 0; q < 8; q++) {
                const float4 vA = *(const float4*)(srcT + b00 + q*4);
                const float4 vB = *(const float4*)(srcT + b10 + q*4);
                const float4 vC = *(const float4*)(srcT + b01 + q*4);
                const float4 vD = *(const float4*)(srcT + b11 + q*4);
                const float s0 = w00*vA.x + w10*vB.x + w01*vC.x + w11*vD.x;
                const float s1 = w00*vA.y + w10*vB.y + w01*vC.y + w11*vD.y;
                const float s2 = w00*vA.z + w10*vB.z + w01*vC.z + w11*vD.z;
                const float s3 = w00*vA.w + w10*vB.w + w01*vC.w + w11*vD.w;
                if (q == 0) vk = (s0 != 0.f) ? 1.f : 0.f;
                const float t = s0*refv[q*4] + s1*refv[q*4+1] + s2*refv[q*4+2] + s3*refv[q*4+3];
                sdk += t;
                wck += t * wregv[q];
            }
            s_d[k] = sdk * 0.25f;   // softmax input: sum_g mean_c
            wcf[k] = wck;           // sum_g wreg[g]*t_g (un-scaled)
            valid[k] = vk;
        }

        // softmax over 32 d: in-register over k, butterfly over d_hi
        float m = s_d[0];
#pragma unroll
        for (int k = 1; k < 8; k++) m = fmaxf(m, s_d[k]);
        m = fmaxf(m, __shfl_xor(m, 16));
        m = fmaxf(m, __shfl_xor(m, 32));

        float e[8];
        float seloc = 0.f, swloc = 0.f;
#pragma unroll
        for (int k = 0; k < 8; k++) {
            e[k] = expf(s_d[k] - m);
            seloc += e[k];
            swloc += src_w * valid[k];
        }
        float se = seloc;
        se += __shfl_xor(se, 16);
        se += __shfl_xor(se, 32);
        float swsum = swloc;
        swsum += __shfl_xor(swsum, 16);
        swsum += __shfl_xor(swsum, 32);

        const float inv_se = 0.17677669529663687f / se;  // softmax/sqrt(C)
#pragma unroll
        for (int k = 0; k < 8; k++) {
            const float cor_w = e[k] * inv_se;
            const float sw = src_w * valid[k];
            acc_logit[k] += cor_w * sw * 0.25f * wcf[k];
            cws[k]  += cor_w;
            sumw[k] += sw;
            nval[k] += valid[k];
        }
        if (dhi == 0) out[OFF_WEIGHT + i*HWc + pix] = swsum * (1.f/32.f);
    }

    // epilogue: final logits + softmax + argmax over 32 d
    const float hrng = 1.f / (hmx - hmn);
    float logit[8];
#pragma unroll
    for (int k = 0; k < 8; k++) {
        logit[k] = acc_logit[k] / (sumw[k] * cws[k]) + (dep[k] - hmn) * hrng;
    }
    float m = logit[0];
#pragma unroll
    for (int k = 1; k < 8; k++) m = fmaxf(m, logit[k]);
    m = fmaxf(m, __shfl_xor(m, 16));
    m = fmaxf(m, __shfl_xor(m, 32));
    float e[8];
    float seloc = 0.f;
#pragma unroll
    for (int k = 0; k < 8; k++) { e[k] = expf(logit[k] - m); seloc += e[k]; }
    float se = seloc;
    se += __shfl_xor(se, 16);
    se += __shfl_xor(se, 32);
    const float inv_se = 1.f / se;

    // argmax (first max on ties): ascending k keeps earliest in-lane
    float av = e[0] * inv_se; int ai = dhi*8;
#pragma unroll
    for (int k = 1; k < 8; k++) {
        const float a = e[k] * inv_se;
        if (a > av) { av = a; ai = dhi*8 + k; }
    }
#pragma unroll
    for (int off = 16; off < 64; off <<= 1) {
        const float av2 = __shfl_xor(av, off);
        const int   ai2 = __shfl_xor(ai, off);
        if (av2 > av || (av2 == av && ai2 < ai)) { av = av2; ai = ai2; }
    }

    // coalesced stores: 16 consecutive px per (d) line
#pragma unroll
    for (int k = 0; k < 8; k++) {
        out[OFF_ATTN + (dhi*8 + k)*HWc + pix] = e[k] * inv_se;
        out[OFF_NVAL + (dhi*8 + k)*HWc + pix] = nval[k];
    }
    if (dhi == 0) {
        const float dep_sel = depth_hypo[ai*HWc + pix];
        const float last_itv = depth_hypo[HWc + pix] - depth_hypo[pix];
        out[OFF_DEPTH + pix] = dep_sel;
        out[OFF_CONF + pix]  = av;
        out[OFF_SW + pix]    = sumw[0] * 0.25f;
        out[OFF_MIN + pix]   = dep_sel - last_itv;
        out[OFF_MAX + pix]   = dep_sel + last_itv;
    }
    if (dhi < 3) {
        float v = np0*w_norm[dhi*3+0] + np1*w_norm[dhi*3+1] + np2*w_norm[dhi*3+2];
        out[OFF_EST + dhi*HWc + pix] = v;
    }
}

extern "C" void kernel_launch(void* const* d_in, const int* in_sizes, int n_in,
                              void* d_out, int out_size, void* d_ws, size_t ws_size,
                              hipStream_t stream) {
    const float* ref   = (const float*)d_in[0];
    const float* src   = (const float*)d_in[1];
    const float* rot   = (const float*)d_in[2];
    const float* np_   = (const float*)d_in[3];
    const float* proj  = (const float*)d_in[4];
    const float* dh    = (const float*)d_in[5];
    const float* wreg  = (const float*)d_in[6];
    const float* wnorm = (const float*)d_in[7];
    float* out = (float*)d_out;
    float* ws  = (float*)d_ws;

    setup_minmax_kernel<<<64, 256, 0, stream>>>(rot, proj, dh, ws);
    transpose_kernel<<<NSRC*(HWc/64), 256, 0, stream>>>(src, ws + WS_SRCT);
    main_kernel<<<NBLK, 64, 0, stream>>>(ref, np_, dh, wreg, wnorm, ws, out);
}